// Round 1
// baseline (1940.125 us; speedup 1.0000x reference)
//
#include <hip/hip_runtime.h>

#define N_TOK 262144
#define DIM 64
#define K_CODES 1024
#define OUT_LOSS_OFF (N_TOK * DIM)      // 16777216
#define OUT_IDX_OFF (N_TOK * DIM + 1)   // 16777217

// Emulates np.sum(x**2) for 64 contiguous fp32 values: numpy pairwise
// summation (8 accumulators, unroll-8, then paired combine). Squares are
// individually rounded (contract OFF prevents x*x+r -> fma fusion).
__device__ __forceinline__ float np_sumsq64(const float* x) {
#pragma clang fp contract(off)
  float r[8];
#pragma unroll
  for (int j = 0; j < 8; ++j) r[j] = x[j] * x[j];
#pragma unroll
  for (int i = 8; i < 64; i += 8) {
#pragma unroll
    for (int j = 0; j < 8; ++j) r[j] += x[i + j] * x[i + j];
  }
  return ((r[0] + r[1]) + (r[2] + r[3])) + ((r[4] + r[5]) + (r[6] + r[7]));
}

// ---------------- main: one thread per token ----------------
// R4 theory: the old fully-unrolled group body asked for 4 codes x 16 float4
// of w in flight -> scheduler pressure estimate exploded -> allocator fell to
// minimize-pressure mode (VGPR_Count=56, zs spilled: +16MB WRITE_SIZE, 2.7x
// VALU inflation). Fix: bound the load window at source level.
//  - k-chunked group body: only 64 w floats in flight per chunk, fenced by
//    sched_barrier(0x7) (ALU crosses freely -> FMA pipelining preserved;
//    VMEM/DS pinned to their chunk).
//  - opaque lane_zero forces w loads to stay VMEM (global_load_dwordx4,
//    broadcast-coalesced) so the fences bind them and the window is visible
//    to the allocator as plain VGPRs.
//  - launch_bounds(256,2): 256-VGPR cap; expect ~150 used -> 3 waves/SIMD.
__global__ __launch_bounds__(256, 2) void vq_main_k(
    const float* __restrict__ z, const float* __restrict__ w,
    float* __restrict__ out, double* __restrict__ loss_acc) {
#pragma clang fp contract(off)
  __shared__ float s_w2[K_CODES];
  __shared__ double red[4];

  // Block-cooperative ||w_c||^2 into LDS, numpy-pairwise bit-exact.
  for (int c0 = 0; c0 < K_CODES; c0 += 256) {
    int c = c0 + (int)threadIdx.x;
    float wl[DIM];
    const float4* wp = (const float4*)(w + (size_t)c * DIM);
#pragma unroll
    for (int i = 0; i < 16; ++i) {
      float4 v = wp[i];
      wl[4 * i + 0] = v.x;
      wl[4 * i + 1] = v.y;
      wl[4 * i + 2] = v.z;
      wl[4 * i + 3] = v.w;
    }
    s_w2[c] = np_sumsq64(wl);
  }
  __syncthreads();

  const int t = blockIdx.x * 256 + (int)threadIdx.x;

  // zs = 2*z resident in 64 VGPRs (doubling is exact; BLAS computed (2z)@wT).
  float zs[DIM];
  {
    const float4* zp = (const float4*)(z + (size_t)t * DIM);
#pragma unroll
    for (int i = 0; i < 16; ++i) {
      float4 v = zp[i];
      zs[4 * i + 0] = v.x + v.x;
      zs[4 * i + 1] = v.y + v.y;
      zs[4 * i + 2] = v.z + v.z;
      zs[4 * i + 3] = v.w + v.w;
    }
  }

  // ||z||^2, numpy-pairwise bit-exact (recover z = 0.5*zs exactly).
  float s_z2;
  {
    float zl[DIM];
#pragma unroll
    for (int k = 0; k < DIM; ++k) zl[k] = 0.5f * zs[k];
    s_z2 = np_sumsq64(zl);
  }

  // Opaque zero: value is 0 but the compiler cannot prove it, so w addresses
  // become lane-variant -> loads stay VMEM (not s_load), bound by the fences.
  int lane_zero;
  asm volatile("v_mov_b32 %0, 0" : "=v"(lane_zero));
  const float* wv = w + lane_zero;

  // Main loop: emulate np's dist = fl(fl(s_z2 + s_w2[c]) - dot2[c]) where
  // dot2 = sequential-k fma chain of (2z_k)*w_k (BLAS sgemm microkernel
  // order). argmin with strict '<' = numpy first-min-wins.
  float best = 3.4e38f;
  int bidx = 0;
#pragma unroll 1
  for (int c = 0; c < K_CODES; c += 4) {
    // wp spans the whole 4-code group: code r, float4 i -> wp[r*16 + i].
    const float4* wp = (const float4*)(wv + (size_t)c * DIM);
    // Prefetch ||w||^2 for the group now; consumed after chunk 3 (4 chunks
    // of latency cover the LDS read).
    float w2_0 = s_w2[c + 0];
    float w2_1 = s_w2[c + 1];
    float w2_2 = s_w2[c + 2];
    float w2_3 = s_w2[c + 3];
    float a0 = 0.f, a1 = 0.f, a2 = 0.f, a3 = 0.f;
#pragma unroll
    for (int ci = 0; ci < 4; ++ci) {
      // Fence: memory ops may not cross (window <= 16 float4 of w in
      // flight); ALU crosses freely so FMAs software-pipeline over the
      // next chunk's loads.
      __builtin_amdgcn_sched_barrier(0x7);
      float4 p0[4], p1[4], p2[4], p3[4];
#pragma unroll
      for (int j = 0; j < 4; ++j) {
        p0[j] = wp[0 * 16 + ci * 4 + j];
        p1[j] = wp[1 * 16 + ci * 4 + j];
        p2[j] = wp[2 * 16 + ci * 4 + j];
        p3[j] = wp[3 * 16 + ci * 4 + j];
      }
      // Strictly ascending k within each chain (4 independent chains).
#pragma unroll
      for (int j = 0; j < 4; ++j) {
        const int k = ci * 16 + 4 * j;
        a0 = __builtin_fmaf(zs[k + 0], p0[j].x, a0);
        a0 = __builtin_fmaf(zs[k + 1], p0[j].y, a0);
        a0 = __builtin_fmaf(zs[k + 2], p0[j].z, a0);
        a0 = __builtin_fmaf(zs[k + 3], p0[j].w, a0);
        a1 = __builtin_fmaf(zs[k + 0], p1[j].x, a1);
        a1 = __builtin_fmaf(zs[k + 1], p1[j].y, a1);
        a1 = __builtin_fmaf(zs[k + 2], p1[j].z, a1);
        a1 = __builtin_fmaf(zs[k + 3], p1[j].w, a1);
        a2 = __builtin_fmaf(zs[k + 0], p2[j].x, a2);
        a2 = __builtin_fmaf(zs[k + 1], p2[j].y, a2);
        a2 = __builtin_fmaf(zs[k + 2], p2[j].z, a2);
        a2 = __builtin_fmaf(zs[k + 3], p2[j].w, a2);
        a3 = __builtin_fmaf(zs[k + 0], p3[j].x, a3);
        a3 = __builtin_fmaf(zs[k + 1], p3[j].y, a3);
        a3 = __builtin_fmaf(zs[k + 2], p3[j].z, a3);
        a3 = __builtin_fmaf(zs[k + 3], p3[j].w, a3);
      }
    }
    float d0 = (s_z2 + w2_0) - a0;  // two separately-rounded fp32 adds
    float d1 = (s_z2 + w2_1) - a1;
    float d2 = (s_z2 + w2_2) - a2;
    float d3 = (s_z2 + w2_3) - a3;
    if (d0 < best) { best = d0; bidx = c + 0; }
    if (d1 < best) { best = d1; bidx = c + 1; }
    if (d2 < best) { best = d2; bidx = c + 2; }
    if (d3 < best) { best = d3; bidx = c + 3; }
  }

  // Epilogue: write z_q (== z_q_st numerically within fp32 threshold), index,
  // and fp64 loss from the final index.
  double ls = 0.0;
  {
    const float4* wq = (const float4*)(wv + (size_t)bidx * DIM);
    float4* op = (float4*)(out + (size_t)t * DIM);
#pragma unroll
    for (int i = 0; i < 16; ++i) {
      float4 v = wq[i];
      op[i] = v;
      double d0 = (double)v.x - 0.5 * (double)zs[4 * i + 0];
      double d1 = (double)v.y - 0.5 * (double)zs[4 * i + 1];
      double d2 = (double)v.z - 0.5 * (double)zs[4 * i + 2];
      double d3 = (double)v.w - 0.5 * (double)zs[4 * i + 3];
      ls = __builtin_fma(d0, d0, ls);
      ls = __builtin_fma(d1, d1, ls);
      ls = __builtin_fma(d2, d2, ls);
      ls = __builtin_fma(d3, d3, ls);
    }
  }
  out[OUT_IDX_OFF + t] = (float)bidx;

  // loss reduce: wave shuffle -> LDS -> one atomic per block
  for (int off = 32; off > 0; off >>= 1) ls += __shfl_down(ls, off, 64);
  if ((threadIdx.x & 63) == 0) red[threadIdx.x >> 6] = ls;
  __syncthreads();
  if (threadIdx.x == 0)
    atomicAdd(loss_acc, (red[0] + red[1]) + (red[2] + red[3]));
}

// ---------------- finalize loss ----------------
__global__ void vq_final_k(const double* __restrict__ loss_acc,
                           float* __restrict__ out) {
  // loss = q_latent + 0.25 * e_latent = 1.25 * mean((z_q - z)^2)
  out[OUT_LOSS_OFF] =
      (float)(1.25 * (*loss_acc) * (1.0 / (double)((size_t)N_TOK * DIM)));
}

extern "C" void kernel_launch(void* const* d_in, const int* in_sizes, int n_in,
                              void* d_out, int out_size, void* d_ws,
                              size_t ws_size, hipStream_t stream) {
  const float* z = (const float*)d_in[0];
  const float* w = (const float*)d_in[1];
  float* out = (float*)d_out;
  double* loss_acc = (double*)d_ws;  // 8 bytes of ws only

  hipMemsetAsync(d_ws, 0, 8, stream);
  vq_main_k<<<N_TOK / 256, 256, 0, stream>>>(z, w, out, loss_acc);
  vq_final_k<<<1, 1, 0, stream>>>(loss_acc, out);
}

// Round 2
// 887.871 us; speedup vs baseline: 2.1851x; 2.1851x over previous
//
#include <hip/hip_runtime.h>

#define N_TOK 262144
#define DIM 64
#define K_CODES 1024
#define OUT_LOSS_OFF (N_TOK * DIM)      // 16777216
#define OUT_IDX_OFF (N_TOK * DIM + 1)   // 16777217

// Emulates np.sum(x**2) for 64 contiguous fp32 values: numpy pairwise
// summation (8 accumulators, unroll-8, then paired combine). Squares are
// individually rounded (contract OFF prevents x*x+r -> fma fusion).
__device__ __forceinline__ float np_sumsq64(const float* x) {
#pragma clang fp contract(off)
  float r[8];
#pragma unroll
  for (int j = 0; j < 8; ++j) r[j] = x[j] * x[j];
#pragma unroll
  for (int i = 8; i < 64; i += 8) {
#pragma unroll
    for (int j = 0; j < 8; ++j) r[j] += x[i + j] * x[i + j];
  }
  return ((r[0] + r[1]) + (r[2] + r[3])) + ((r[4] + r[5]) + (r[6] + r[7]));
}

// ---------------- main: one thread per token ----------------
// R5 theory: the 773us baseline already had the right structure -- w is
// wave-uniform so the compiler emits s_load_dwordx16 (SGPR_Count=112) and
// FMAs take w from the free SGPR operand; the ONLY defect was zs[64]
// spilling (VGPR_Count=56: launch_bounds' 2nd arg is a MIN waves/EU, i.e.
// only an upper bound on VGPRs -- the allocator still targeted ~8 waves/EU).
// R4's opaque-zero+sched_barrier attempt destroyed the scalar path
// (SGPR 112->32) and latency hiding (VALUBusy 26%): reverted entirely.
// Fix: amdgpu_waves_per_eu(2,4) -- max=4 caps the allocator's occupancy
// target, giving a 128-VGPR budget so zs stays resident; 4 waves/EU (50%
// occupancy) still exceeds the baseline's 34%.
__global__ __attribute__((amdgpu_flat_work_group_size(256, 256),
                          amdgpu_waves_per_eu(2, 4))) void vq_main_k(
    const float* __restrict__ z, const float* __restrict__ w,
    float* __restrict__ out, double* __restrict__ loss_acc) {
#pragma clang fp contract(off)
  __shared__ float s_w2[K_CODES];
  __shared__ double red[4];

  // Block-cooperative ||w_c||^2 into LDS, numpy-pairwise bit-exact.
  for (int c0 = 0; c0 < K_CODES; c0 += 256) {
    int c = c0 + (int)threadIdx.x;
    float wl[DIM];
    const float4* wp = (const float4*)(w + (size_t)c * DIM);
#pragma unroll
    for (int i = 0; i < 16; ++i) {
      float4 v = wp[i];
      wl[4 * i + 0] = v.x;
      wl[4 * i + 1] = v.y;
      wl[4 * i + 2] = v.z;
      wl[4 * i + 3] = v.w;
    }
    s_w2[c] = np_sumsq64(wl);
  }
  __syncthreads();

  const int t = blockIdx.x * 256 + (int)threadIdx.x;

  // zs = 2*z resident in 64 VGPRs (doubling is exact; BLAS computed (2z)@wT).
  float zs[DIM];
  {
    const float4* zp = (const float4*)(z + (size_t)t * DIM);
#pragma unroll
    for (int i = 0; i < 16; ++i) {
      float4 v = zp[i];
      zs[4 * i + 0] = v.x + v.x;
      zs[4 * i + 1] = v.y + v.y;
      zs[4 * i + 2] = v.z + v.z;
      zs[4 * i + 3] = v.w + v.w;
    }
  }

  // ||z||^2, numpy-pairwise bit-exact (recover z = 0.5*zs exactly).
  float s_z2;
  {
    float zl[DIM];
#pragma unroll
    for (int k = 0; k < DIM; ++k) zl[k] = 0.5f * zs[k];
    s_z2 = np_sumsq64(zl);
  }

  // Main loop: emulate np's dist = fl(fl(s_z2 + s_w2[c]) - dot2[c]) where
  // dot2 = sequential-k fma chain of (2z_k)*w_k (BLAS sgemm microkernel
  // order). argmin with strict '<' = numpy first-min-wins.
  // w addresses are wave-uniform on purpose: the compiler turns these into
  // s_load_dwordx16 and feeds FMAs from SGPRs (1 SGPR operand is free).
  float best = 3.4e38f;
  int bidx = 0;
#pragma unroll 1
  for (int c = 0; c < K_CODES; c += 4) {
    const float4* w0 = (const float4*)(w + (size_t)c * DIM);
    const float4* w1 = (const float4*)(w + (size_t)(c + 1) * DIM);
    const float4* w2 = (const float4*)(w + (size_t)(c + 2) * DIM);
    const float4* w3 = (const float4*)(w + (size_t)(c + 3) * DIM);
    float a0 = 0.f, a1 = 0.f, a2 = 0.f, a3 = 0.f;
#pragma unroll
    for (int i = 0; i < 16; ++i) {
      float4 p0 = w0[i];
      float4 p1 = w1[i];
      float4 p2 = w2[i];
      float4 p3 = w3[i];
      // strictly ascending k within each chain (4 independent chains for ILP)
      a0 = __builtin_fmaf(zs[4 * i + 0], p0.x, a0);
      a0 = __builtin_fmaf(zs[4 * i + 1], p0.y, a0);
      a0 = __builtin_fmaf(zs[4 * i + 2], p0.z, a0);
      a0 = __builtin_fmaf(zs[4 * i + 3], p0.w, a0);
      a1 = __builtin_fmaf(zs[4 * i + 0], p1.x, a1);
      a1 = __builtin_fmaf(zs[4 * i + 1], p1.y, a1);
      a1 = __builtin_fmaf(zs[4 * i + 2], p1.z, a1);
      a1 = __builtin_fmaf(zs[4 * i + 3], p1.w, a1);
      a2 = __builtin_fmaf(zs[4 * i + 0], p2.x, a2);
      a2 = __builtin_fmaf(zs[4 * i + 1], p2.y, a2);
      a2 = __builtin_fmaf(zs[4 * i + 2], p2.z, a2);
      a2 = __builtin_fmaf(zs[4 * i + 3], p2.w, a2);
      a3 = __builtin_fmaf(zs[4 * i + 0], p3.x, a3);
      a3 = __builtin_fmaf(zs[4 * i + 1], p3.y, a3);
      a3 = __builtin_fmaf(zs[4 * i + 2], p3.z, a3);
      a3 = __builtin_fmaf(zs[4 * i + 3], p3.w, a3);
    }
    float d0 = (s_z2 + s_w2[c + 0]) - a0;  // two separately-rounded fp32 adds
    float d1 = (s_z2 + s_w2[c + 1]) - a1;
    float d2 = (s_z2 + s_w2[c + 2]) - a2;
    float d3 = (s_z2 + s_w2[c + 3]) - a3;
    if (d0 < best) { best = d0; bidx = c + 0; }
    if (d1 < best) { best = d1; bidx = c + 1; }
    if (d2 < best) { best = d2; bidx = c + 2; }
    if (d3 < best) { best = d3; bidx = c + 3; }
  }

  // Epilogue: write z_q (== z_q_st numerically within fp32 threshold), index,
  // and fp64 loss from the final index.
  double ls = 0.0;
  {
    const float4* wq = (const float4*)(w + (size_t)bidx * DIM);
    float4* op = (float4*)(out + (size_t)t * DIM);
#pragma unroll
    for (int i = 0; i < 16; ++i) {
      float4 v = wq[i];
      op[i] = v;
      double d0 = (double)v.x - 0.5 * (double)zs[4 * i + 0];
      double d1 = (double)v.y - 0.5 * (double)zs[4 * i + 1];
      double d2 = (double)v.z - 0.5 * (double)zs[4 * i + 2];
      double d3 = (double)v.w - 0.5 * (double)zs[4 * i + 3];
      ls = __builtin_fma(d0, d0, ls);
      ls = __builtin_fma(d1, d1, ls);
      ls = __builtin_fma(d2, d2, ls);
      ls = __builtin_fma(d3, d3, ls);
    }
  }
  out[OUT_IDX_OFF + t] = (float)bidx;

  // loss reduce: wave shuffle -> LDS -> one atomic per block
  for (int off = 32; off > 0; off >>= 1) ls += __shfl_down(ls, off, 64);
  if ((threadIdx.x & 63) == 0) red[threadIdx.x >> 6] = ls;
  __syncthreads();
  if (threadIdx.x == 0)
    atomicAdd(loss_acc, (red[0] + red[1]) + (red[2] + red[3]));
}

// ---------------- finalize loss ----------------
__global__ void vq_final_k(const double* __restrict__ loss_acc,
                           float* __restrict__ out) {
  // loss = q_latent + 0.25 * e_latent = 1.25 * mean((z_q - z)^2)
  out[OUT_LOSS_OFF] =
      (float)(1.25 * (*loss_acc) * (1.0 / (double)((size_t)N_TOK * DIM)));
}

extern "C" void kernel_launch(void* const* d_in, const int* in_sizes, int n_in,
                              void* d_out, int out_size, void* d_ws,
                              size_t ws_size, hipStream_t stream) {
  const float* z = (const float*)d_in[0];
  const float* w = (const float*)d_in[1];
  float* out = (float*)d_out;
  double* loss_acc = (double*)d_ws;  // 8 bytes of ws only

  hipMemsetAsync(d_ws, 0, 8, stream);
  vq_main_k<<<N_TOK / 256, 256, 0, stream>>>(z, w, out, loss_acc);
  vq_final_k<<<1, 1, 0, stream>>>(loss_acc, out);
}

// Round 3
// 440.453 us; speedup vs baseline: 4.4048x; 2.0158x over previous
//
#include <hip/hip_runtime.h>
#include <stdint.h>

#define N_TOK 262144
#define DIM 64
#define K_CODES 1024
#define OUT_LOSS_OFF (N_TOK * DIM)      // 16777216
#define OUT_IDX_OFF (N_TOK * DIM + 1)   // 16777217

// Certified |d_approx - d_exact| <= ~1.1e-4 worst case (fp16 w-term
// 2^-11*||2z||*||w|| <= 8.9e-5 at ||z||<=11.5, + outer rounding 1.5e-5,
// + split residuals ~1e-7). MARGIN = 4e-4 gives 1.8x headroom.
#define MARGIN 4e-4f

typedef _Float16 half8 __attribute__((ext_vector_type(8)));
typedef float f32x4 __attribute__((ext_vector_type(4)));
typedef unsigned int uint32x4 __attribute__((ext_vector_type(4)));

// ---- LDS layout (byte offsets into one block) ----
#define SM_WF 0          // fp16 w*1024, 1024 rows x 128B, chunk-XOR swizzled
#define SM_SW2 131072    // float[1024]  ||w_c||^2 (np-pairwise exact)
#define SM_SZ2 135168    // float[256]   ||z_t||^2 (np-pairwise exact)
#define SM_M1 136192     // float[256] screening top-4 values + 3 indices
#define SM_M2 137216
#define SM_M3 138240
#define SM_M4 139264
#define SM_I1 140288
#define SM_I2 141312
#define SM_I3 142336
#define SM_IDX 143360    // int[256] final index per token
#define SM_FBC 144384    // int fallback counter
#define SM_FBL 144388    // int[256] fallback token list
#define SM_RED 145416    // double[16] loss partials
#define SM_FBK 145544    // u64 fallback argmin key
#define SM_BYTES 145552

// numpy pairwise sum of squares, 64 contiguous fp32 (bit-exact vs reference)
__device__ __forceinline__ float np_sumsq64(const float* x) {
#pragma clang fp contract(off)
  float r[8];
#pragma unroll
  for (int j = 0; j < 8; ++j) r[j] = x[j] * x[j];
#pragma unroll
  for (int i = 8; i < 64; i += 8) {
#pragma unroll
    for (int j = 0; j < 8; ++j) r[j] += x[i + j] * x[i + j];
  }
  return ((r[0] + r[1]) + (r[2] + r[3])) + ((r[4] + r[5]) + (r[6] + r[7]));
}

// The ORIGINAL bit-exact distance: d = fl(fl(s_z2+s_w2) - chain64((2z)*w)),
// sequential ascending k. Must match numpy/BLAS exactly -> argmin-identical.
__device__ __forceinline__ float exact_dist(const float* __restrict__ z,
                                            long long t, int c,
                                            const float* __restrict__ w,
                                            float s_z2v, float w2) {
  const float4* zp = (const float4*)(z + (size_t)t * DIM);
  const float4* wp = (const float4*)(w + (size_t)c * DIM);
  float a = 0.f;
#pragma unroll
  for (int i = 0; i < 16; ++i) {
    float4 zv = zp[i];
    float4 pv = wp[i];
    a = __builtin_fmaf(zv.x + zv.x, pv.x, a);
    a = __builtin_fmaf(zv.y + zv.y, pv.y, a);
    a = __builtin_fmaf(zv.z + zv.z, pv.z, a);
    a = __builtin_fmaf(zv.w + zv.w, pv.w, a);
  }
  return (s_z2v + w2) - a;
}

// Branchless sorted insert into 4-deep (values) / 3-deep (indices) list.
__device__ __forceinline__ void ins4(float d, int c, float& m1, float& m2,
                                     float& m3, float& m4, int& i1, int& i2,
                                     int& i3) {
  bool b1 = d < m1, b2 = d < m2, b3 = d < m3, b4 = d < m4;
  m4 = b3 ? m3 : (b4 ? d : m4);
  m3 = b2 ? m2 : (b3 ? d : m3);
  i3 = b2 ? i2 : (b3 ? c : i3);
  m2 = b1 ? m1 : (b2 ? d : m2);
  i2 = b1 ? i1 : (b2 ? c : i2);
  m1 = b1 ? d : m1;
  i1 = b1 ? c : i1;
}

// Build one k-half MFMA A-frag pair from 8 z floats: hi = fp16(2z),
// lo = fp16((2z - hi) * 4096). dot = acc_h*2^-0... recombined with exact
// power-of-2 scales later (w is scaled by 1024 -> C1=2^-10, C2=2^-22).
__device__ __forceinline__ void make_afrag(float4 a, float4 b, half8& hi,
                                           half8& lo) {
  float v[8] = {a.x, a.y, a.z, a.w, b.x, b.y, b.z, b.w};
  uint32x4 uh, ul;
#pragma unroll
  for (int j = 0; j < 4; ++j) {
    float x0 = v[2 * j] + v[2 * j];
    float x1 = v[2 * j + 1] + v[2 * j + 1];
    _Float16 h0 = (_Float16)x0, h1 = (_Float16)x1;
    float r0 = (x0 - (float)h0) * 4096.f;
    float r1 = (x1 - (float)h1) * 4096.f;
    _Float16 l0 = (_Float16)r0, l1 = (_Float16)r1;
    uh[j] = (unsigned)__builtin_bit_cast(unsigned short, h0) |
            ((unsigned)__builtin_bit_cast(unsigned short, h1) << 16);
    ul[j] = (unsigned)__builtin_bit_cast(unsigned short, l0) |
            ((unsigned)__builtin_bit_cast(unsigned short, l1) << 16);
  }
  hi = __builtin_bit_cast(half8, uh);
  lo = __builtin_bit_cast(half8, ul);
}

// One block = 256 tokens, 1024 threads (16 waves). Screen all 1024 codes via
// mfma_f32_16x16x32_f16 (wave: 16 tokens x 16-code tiles), track top-4, then
// exact-eval only margin candidates with the original bit-exact chain.
__global__ __launch_bounds__(1024) void vq_main_k(
    const float* __restrict__ z, const float* __restrict__ w,
    float* __restrict__ out, double* __restrict__ loss_acc) {
#pragma clang fp contract(off)
  __shared__ __align__(16) char smem[SM_BYTES];
  char* wf = smem + SM_WF;
  float* sw2 = (float*)(smem + SM_SW2);
  float* sz2 = (float*)(smem + SM_SZ2);
  float* sm1 = (float*)(smem + SM_M1);
  float* sm2 = (float*)(smem + SM_M2);
  float* sm3 = (float*)(smem + SM_M3);
  float* sm4 = (float*)(smem + SM_M4);
  int* si1 = (int*)(smem + SM_I1);
  int* si2 = (int*)(smem + SM_I2);
  int* si3 = (int*)(smem + SM_I3);
  int* sidx = (int*)(smem + SM_IDX);
  int* fbc = (int*)(smem + SM_FBC);
  int* fbl = (int*)(smem + SM_FBL);
  double* red = (double*)(smem + SM_RED);
  unsigned long long* fbk = (unsigned long long*)(smem + SM_FBK);

  const int tid = (int)threadIdx.x;
  const int lane = tid & 63;
  const int wid = tid >> 6;  // 16 waves

  if (tid == 0) *fbc = 0;

  // ---- prologue A: per-code ||w||^2 + fp16(w*1024) staged to LDS ----
  {
    const int c = tid;  // 1024 threads = 1024 codes
    const float4* wp = (const float4*)(w + (size_t)c * DIM);
    float wl[DIM];
#pragma unroll
    for (int i = 0; i < 16; ++i) {
      float4 v = wp[i];
      wl[4 * i + 0] = v.x;
      wl[4 * i + 1] = v.y;
      wl[4 * i + 2] = v.z;
      wl[4 * i + 3] = v.w;
    }
    sw2[c] = np_sumsq64(wl);
    // chunk ch holds k = ch*8..+7; stored at slot ch^(c&7) (bank-balanced)
#pragma unroll
    for (int ch = 0; ch < 8; ++ch) {
      uint32x4 pk;
#pragma unroll
      for (int j = 0; j < 4; ++j) {
        _Float16 h0 = (_Float16)(wl[ch * 8 + 2 * j] * 1024.f);
        _Float16 h1 = (_Float16)(wl[ch * 8 + 2 * j + 1] * 1024.f);
        pk[j] = (unsigned)__builtin_bit_cast(unsigned short, h0) |
                ((unsigned)__builtin_bit_cast(unsigned short, h1) << 16);
      }
      *(uint32x4*)(wf + c * 128 + ((ch ^ (c & 7)) << 4)) = pk;
    }
  }
  // ---- prologue B: per-token ||z||^2 (np-pairwise exact) ----
  if (tid < 256) {
    long long gt = (long long)blockIdx.x * 256 + tid;
    const float4* zp = (const float4*)(z + (size_t)gt * DIM);
    float zl[DIM];
#pragma unroll
    for (int i = 0; i < 16; ++i) {
      float4 v = zp[i];
      zl[4 * i + 0] = v.x;
      zl[4 * i + 1] = v.y;
      zl[4 * i + 2] = v.z;
      zl[4 * i + 3] = v.w;
    }
    sz2[tid] = np_sumsq64(zl);
  }
  __syncthreads();

  // ---- screening: wave handles 16 tokens x all 1024 codes ----
  {
    const int wtok = wid * 16;
    const int g = lane >> 4;  // k-group
    // A-frags: token = wtok + (lane&15), k = g*8..+7 (khalf0), 32+g*8 (khalf1)
    half8 ah0, al0, ah1, al1;
    {
      long long gA = ((long long)blockIdx.x * 256 + wtok + (lane & 15)) * DIM;
      const float* zr = z + gA + g * 8;
      make_afrag(*(const float4*)(zr), *(const float4*)(zr + 4), ah0, al0);
      make_afrag(*(const float4*)(zr + 32), *(const float4*)(zr + 36), ah1,
                 al1);
    }
    // acc rows: token = wtok + g*4 + r
    float sz[4];
#pragma unroll
    for (int r = 0; r < 4; ++r) sz[r] = sz2[wtok + g * 4 + r];

    float m1[4], m2[4], m3[4], m4[4];
    int i1[4], i2[4], i3[4];
#pragma unroll
    for (int r = 0; r < 4; ++r) {
      m1[r] = m2[r] = m3[r] = m4[r] = 3.4e38f;
      i1[r] = i2[r] = i3[r] = 0;
    }

    const float C1 = 1.f / 1024.f;            // undo w*1024
    const float C2 = 1.f / (1024.f * 4096.f); // undo w*1024 and zlo*4096

#pragma unroll 2
    for (int ct = 0; ct < 64; ++ct) {
      const int cc = (ct << 4) | (lane & 15);
      float w2c = sw2[cc];
      const char* wrow = wf + cc * 128;
      half8 b0 = __builtin_bit_cast(
          half8, *(const uint32x4*)(wrow + ((g ^ (cc & 7)) << 4)));
      half8 b1 = __builtin_bit_cast(
          half8, *(const uint32x4*)(wrow + (((4 + g) ^ (cc & 7)) << 4)));
      f32x4 acch = {0.f, 0.f, 0.f, 0.f};
      f32x4 accl = {0.f, 0.f, 0.f, 0.f};
      acch = __builtin_amdgcn_mfma_f32_16x16x32_f16(ah0, b0, acch, 0, 0, 0);
      accl = __builtin_amdgcn_mfma_f32_16x16x32_f16(al0, b0, accl, 0, 0, 0);
      acch = __builtin_amdgcn_mfma_f32_16x16x32_f16(ah1, b1, acch, 0, 0, 0);
      accl = __builtin_amdgcn_mfma_f32_16x16x32_f16(al1, b1, accl, 0, 0, 0);
#pragma unroll
      for (int r = 0; r < 4; ++r) {
        float dot = __builtin_fmaf(accl[r], C2, acch[r] * C1);
        float d = (sz[r] + w2c) - dot;
        ins4(d, cc, m1[r], m2[r], m3[r], m4[r], i1[r], i2[r], i3[r]);
      }
    }

    // butterfly merge across the 16 lanes sharing this token set
#pragma unroll
    for (int s = 1; s <= 8; s <<= 1) {
#pragma unroll
      for (int r = 0; r < 4; ++r) {
        float bm1 = __shfl_xor(m1[r], s, 64);
        float bm2 = __shfl_xor(m2[r], s, 64);
        float bm3 = __shfl_xor(m3[r], s, 64);
        float bm4 = __shfl_xor(m4[r], s, 64);
        int bi1 = __shfl_xor(i1[r], s, 64);
        int bi2 = __shfl_xor(i2[r], s, 64);
        int bi3 = __shfl_xor(i3[r], s, 64);
        ins4(bm1, bi1, m1[r], m2[r], m3[r], m4[r], i1[r], i2[r], i3[r]);
        ins4(bm2, bi2, m1[r], m2[r], m3[r], m4[r], i1[r], i2[r], i3[r]);
        ins4(bm3, bi3, m1[r], m2[r], m3[r], m4[r], i1[r], i2[r], i3[r]);
        m4[r] = fminf(m4[r], bm4);
      }
    }
    if ((lane & 15) == 0) {
#pragma unroll
      for (int r = 0; r < 4; ++r) {
        int tk = wtok + g * 4 + r;
        sm1[tk] = m1[r];
        sm2[tk] = m2[r];
        sm3[tk] = m3[r];
        sm4[tk] = m4[r];
        si1[tk] = i1[r];
        si2[tk] = i2[r];
        si3[tk] = i3[r];
      }
    }
  }
  __syncthreads();

  // ---- phase 1: resolve index per token (threads 0..255) ----
  if (tid < 256) {
    const int tok = tid;
    float v1 = sm1[tok], v2 = sm2[tok], v3 = sm3[tok], v4 = sm4[tok];
    float thr = v1 + MARGIN;
    int idx = si1[tok];
    if (v2 <= thr) {
      if (v4 <= thr) {
        // >=4 candidates in margin: rare, full exact scan cooperatively later
        int p = atomicAdd(fbc, 1);
        fbl[p] = tok;
        idx = -1;
      } else {
        long long gt = (long long)blockIdx.x * 256 + tok;
        float sz2v = sz2[tok];
        int ca = si1[tok], cb = si2[tok], cc2 = si3[tok];
        int n = (v3 <= thr) ? 3 : 2;
        int t;
        if (cb < ca) { t = ca; ca = cb; cb = t; }
        if (n == 3) {
          if (cc2 < cb) { t = cb; cb = cc2; cc2 = t; }
          if (cb < ca) { t = ca; ca = cb; cb = t; }
        }
        // exact eval ascending index, strict '<' => numpy first-min-wins
        float bd = exact_dist(z, gt, ca, w, sz2v, sw2[ca]);
        idx = ca;
        float d2 = exact_dist(z, gt, cb, w, sz2v, sw2[cb]);
        if (d2 < bd) { bd = d2; idx = cb; }
        if (n == 3) {
          float d3 = exact_dist(z, gt, cc2, w, sz2v, sw2[cc2]);
          if (d3 < bd) { bd = d3; idx = cc2; }
        }
      }
    }
    if (idx >= 0) sidx[tok] = idx;
  }
  __syncthreads();

  // ---- phase 2: cooperative exact fallback (expected ~0 per block) ----
  {
    int nfb = *fbc;
    for (int f = 0; f < nfb; ++f) {
      int tok = fbl[f];
      if (tid == 0) *fbk = ~0ull;
      __syncthreads();
      long long gt = (long long)blockIdx.x * 256 + tok;
      float d = exact_dist(z, gt, tid, w, sz2[tok], sw2[tid]);
      // positive d: float bit pattern is order-preserving; idx in low bits
      unsigned long long key =
          ((unsigned long long)__builtin_bit_cast(unsigned int, d) << 32) |
          (unsigned)tid;
#pragma unroll
      for (int off = 32; off > 0; off >>= 1) {
        unsigned long long o = __shfl_down(key, off, 64);
        key = (o < key) ? o : key;
      }
      if (lane == 0) atomicMin(fbk, key);
      __syncthreads();
      if (tid == 0) sidx[tok] = (int)((*fbk) & 0xffffffffu);
    }
  }
  __syncthreads();

  // ---- phase 3: outputs. thread -> (token, quarter of 16 floats) ----
  {
    const int tok = tid >> 2, q = tid & 3;
    const long long gt = (long long)blockIdx.x * 256 + tok;
    const int idx = sidx[tok];
    const float4* zp = (const float4*)(z + (size_t)gt * DIM) + q * 4;
    const float4* wp = (const float4*)(w + (size_t)idx * DIM) + q * 4;
    float4* op = (float4*)(out + (size_t)gt * DIM) + q * 4;
    double ls = 0.0;
#pragma unroll
    for (int i = 0; i < 4; ++i) {
      float4 wv = wp[i];
      float4 zv = zp[i];
      op[i] = wv;
      double d0 = (double)wv.x - (double)zv.x;
      double d1 = (double)wv.y - (double)zv.y;
      double d2 = (double)wv.z - (double)zv.z;
      double d3 = (double)wv.w - (double)zv.w;
      ls = __builtin_fma(d0, d0, ls);
      ls = __builtin_fma(d1, d1, ls);
      ls = __builtin_fma(d2, d2, ls);
      ls = __builtin_fma(d3, d3, ls);
    }
    if (q == 0) out[OUT_IDX_OFF + gt] = (float)idx;
#pragma unroll
    for (int off = 32; off > 0; off >>= 1) ls += __shfl_down(ls, off, 64);
    if (lane == 0) red[wid] = ls;
    __syncthreads();
    if (tid == 0) {
      double s = 0.0;
#pragma unroll
      for (int i = 0; i < 16; ++i) s += red[i];
      atomicAdd(loss_acc, s);
    }
  }
}

// ---------------- finalize loss ----------------
__global__ void vq_final_k(const double* __restrict__ loss_acc,
                           float* __restrict__ out) {
  out[OUT_LOSS_OFF] =
      (float)(1.25 * (*loss_acc) * (1.0 / (double)((size_t)N_TOK * DIM)));
}

extern "C" void kernel_launch(void* const* d_in, const int* in_sizes, int n_in,
                              void* d_out, int out_size, void* d_ws,
                              size_t ws_size, hipStream_t stream) {
  const float* z = (const float*)d_in[0];
  const float* w = (const float*)d_in[1];
  float* out = (float*)d_out;
  double* loss_acc = (double*)d_ws;  // 8 bytes of ws only

  hipMemsetAsync(d_ws, 0, 8, stream);
  vq_main_k<<<N_TOK / 256, 1024, 0, stream>>>(z, w, out, loss_acc);
  vq_final_k<<<1, 1, 0, stream>>>(loss_acc, out);
}